// Round 5
// baseline (176.474 us; speedup 1.0000x reference)
//
#include <hip/hip_runtime.h>
#include <hip/hip_cooperative_groups.h>
#include <stdint.h>

typedef unsigned int uint32;
typedef unsigned long long u64;
typedef short bf16x8 __attribute__((ext_vector_type(8)));
typedef float f32x4 __attribute__((ext_vector_type(4)));

// fp32 -> bf16 bits, round-to-nearest-even
__device__ __forceinline__ unsigned short f2bf(float f) {
  uint32 u = __builtin_bit_cast(uint32, f);
  u += 0x7FFFu + ((u >> 16) & 1u);
  return (unsigned short)(u >> 16);
}

// ---------------------------------------------------------------------------
// K1: h = X*W (16384x128 @ 128x64), e_src/e_dst = h.a, store
//   hTt : bf16, k-blocked layout [B][i>>3][d][i&7]  (256KB/batch)
//   E1 = exp(e_dst), E2 = exp(0.2 e_dst)   (per j)
//   ET = exp(-e_src), G = exp(0.8 e_src)   (per i)
// ---------------------------------------------------------------------------
__global__ __launch_bounds__(256) void k1_h_e(
    const float* __restrict__ X, const float* __restrict__ W,
    const float* __restrict__ A, const float* __restrict__ mask,
    unsigned short* __restrict__ hTt,
    float* __restrict__ E1, float* __restrict__ E2,
    float* __restrict__ ET, float* __restrict__ G) {
  __shared__ float WT[64][132];
  const int t = threadIdx.x;
  for (int idx = t; idx < 128 * 64; idx += 256) {
    int k = idx >> 6, d = idx & 63;
    WT[d][k] = W[idx];
  }
  __syncthreads();

  const int dg = t & 15;
  const int rp = t >> 4;
  const int gi0 = blockIdx.x * 32 + rp * 2;

  float a1[4], a2[4];
#pragma unroll
  for (int dd = 0; dd < 4; ++dd) {
    a1[dd] = A[dg + 16 * dd];
    a2[dd] = A[64 + dg + 16 * dd];
  }

  const float4* x0 = (const float4*)(X + (size_t)gi0 * 128);
  const float4* x1 = (const float4*)(X + (size_t)(gi0 + 1) * 128);
  float h0[4] = {0.f, 0.f, 0.f, 0.f}, h1[4] = {0.f, 0.f, 0.f, 0.f};
#pragma unroll 4
  for (int kq = 0; kq < 32; ++kq) {
    const float4 xa = x0[kq], xb = x1[kq];
#pragma unroll
    for (int dd = 0; dd < 4; ++dd) {
      const float4 w4 = *(const float4*)(&WT[dg + 16 * dd][kq * 4]);
      h0[dd] += xa.x * w4.x + xa.y * w4.y + xa.z * w4.z + xa.w * w4.w;
      h1[dd] += xb.x * w4.x + xb.y * w4.y + xb.z * w4.z + xb.w * w4.w;
    }
  }

  float es0 = 0.f, ed0 = 0.f, es1 = 0.f, ed1 = 0.f;
#pragma unroll
  for (int dd = 0; dd < 4; ++dd) {
    es0 += h0[dd] * a1[dd]; ed0 += h0[dd] * a2[dd];
    es1 += h1[dd] * a1[dd]; ed1 += h1[dd] * a2[dd];
  }
#pragma unroll
  for (int m = 1; m < 16; m <<= 1) {
    es0 += __shfl_xor(es0, m, 64);
    ed0 += __shfl_xor(ed0, m, 64);
    es1 += __shfl_xor(es1, m, 64);
    ed1 += __shfl_xor(ed1, m, 64);
  }
  if (dg == 0) {
    ET[gi0] = expf(-es0);      G[gi0] = expf(0.8f * es0);
    E1[gi0] = expf(ed0);       E2[gi0] = expf(0.2f * ed0);
    ET[gi0 + 1] = expf(-es1);  G[gi0 + 1] = expf(0.8f * es1);
    E1[gi0 + 1] = expf(ed1);   E2[gi0 + 1] = expf(0.2f * ed1);
  }

  const float m0 = mask[gi0], m1 = mask[gi0 + 1];
  const int b = gi0 >> 11, i = gi0 & 2047;
  const int ib = i >> 3, io = i & 7;
#pragma unroll
  for (int dd = 0; dd < 4; ++dd) {
    const int d = dg + 16 * dd;
    const uint32 lo = f2bf(h0[dd] * m0);
    const uint32 hi = f2bf(h1[dd] * m1);
    *(uint32*)(hTt + ((size_t)b << 17) + (ib << 9) + (d << 3) + io) = lo | (hi << 16);
  }
}

// ---------------------------------------------------------------------------
// KF (cooperative, fused k3+k4):
//   Phase 3: stream adj once (128MB); per row i compute S1/S2 sums, packed
//            bf16 PP, and adjacency bit-planes bitA/bitB. Bits/PP stay in
//            cache — produced & consumed inside this kernel (no HBM trip).
//   grid sync (device fence -> visible across XCDs regardless of placement)
//   Phase 4: h'[j,d] = sum_i p[i,j]*h[i,d] via MFMA + in-block K-split
//            reduce + ELU. batch = bid&7 in BOTH phases -> XCD-local reuse
//            when dispatch round-robins XCDs (heuristic, not correctness).
// ---------------------------------------------------------------------------
__global__ __launch_bounds__(512) void kf_fused(
    const int* __restrict__ adj, const unsigned short* __restrict__ hTt,
    const float* __restrict__ E1, const float* __restrict__ E2,
    const float* __restrict__ ET, const float* __restrict__ G,
    uint32* __restrict__ bitA, uint32* __restrict__ bitB,
    uint32* __restrict__ PP, float* __restrict__ out) {
  __shared__ float sAcc[3][32][68];
  const int t = threadIdx.x;
  const int w = t >> 6, l = t & 63;
  const int b = blockIdx.x & 7;  // grid is a multiple of 8

  // ---------------- Phase 3 ----------------
  {
    const float4* e1p = (const float4*)(E1 + b * 2048);
    const float4* e2p = (const float4*)(E2 + b * 2048);
    for (int g = blockIdx.x; g < 2048; g += gridDim.x) {
      const int i = (g >> 3) * 8 + w;      // g & 7 == b
      const int gi = b * 2048 + i;
      const float eti = ET[gi];
      const int4* arow = (const int4*)(adj + (size_t)gi * 2048);
      float s1 = 0.f, s2 = 0.f;
#pragma unroll
      for (int jc = 0; jc < 8; ++jc) {
        const int idx = jc * 64 + l;
        const int4 av = arow[idx];
        const float4 e1 = e1p[idx];
        const float4 e2 = e2p[idx];
        const bool m0 = (av.x == 1), m1b = (av.y == 1), m2 = (av.z == 1), m3 = (av.w == 1);
        const bool q0 = (e1.x > eti), q1 = (e1.y > eti), q2 = (e1.z > eti), q3 = (e1.w > eti);
        s1 += (m0 && q0) ? e1.x : 0.f;   s2 += (m0 && !q0) ? e2.x : 0.f;
        s1 += (m1b && q1) ? e1.y : 0.f;  s2 += (m1b && !q1) ? e2.y : 0.f;
        s1 += (m2 && q2) ? e1.z : 0.f;   s2 += (m2 && !q2) ? e2.z : 0.f;
        s1 += (m3 && q3) ? e1.w : 0.f;   s2 += (m3 && !q3) ? e2.w : 0.f;
        const u64 b0 = __ballot(m0), b1 = __ballot(m1b), b2 = __ballot(m2), b3 = __ballot(m3);
        if (l < 4) {
          const u64 v = (l == 0) ? b0 : (l == 1) ? b1 : (l == 2) ? b2 : b3;
          const size_t off = (size_t)(b * 32 + jc * 4 + l) * 2048 + i;
          bitA[off] = (uint32)v;
          bitB[off] = (uint32)(v >> 32);
        }
      }
#pragma unroll
      for (int m = 1; m < 64; m <<= 1) {
        s1 += __shfl_xor(s1, m, 64);
        s2 += __shfl_xor(s2, m, 64);
      }
      if (l == 0) {
        const float g2 = G[gi];
        const bool ok = (s1 + s2) > 0.f;
        const float p1 = ok ? 1.f / (s1 + s2 / g2) : 0.f;
        const float p2 = ok ? 1.f / (s1 * g2 + s2) : 0.f;
        PP[gi] = (uint32)f2bf(p1) | ((uint32)f2bf(p2) << 16);
      }
    }
  }

  __threadfence();  // device-scope release (L2 writeback on gfx9xx)
  cooperative_groups::this_grid().sync();

  // ---------------- Phase 4 ----------------
  {
    const int wj = w & 1, wk = w >> 1;
    const int kg = l >> 4;
    const float* ETb = ET + b * 2048;
    const uint32* PPb = PP + b * 2048;
    const unsigned short* hTtb = hTt + ((size_t)b << 17);
    float* outb = out + ((size_t)b << 17);

    for (int u = blockIdx.x; u < 512; u += gridDim.x) {
      const int jt = u >> 3;               // u & 7 == b
      const int J0 = jt * 32 + wj * 16;
      const int jj = J0 + (l & 15);

      const float rE1 = E1[b * 2048 + jj];
      const float rE2 = E2[b * 2048 + jj];
      const int widx = ((jj >> 8) << 2) + (jj & 3);
      const size_t rowoff = (size_t)(b * 32 + widx) * 2048;
      const int sh = (jj >> 2) & 63;       // wave-uniform (J0 % 16 == 0)
      const uint32 maskbit = 1u << (sh & 31);
      const uint32* bp = ((sh >= 32) ? bitB : bitA) + rowoff;

      f32x4 acc[4] = {};

      for (int kt = 0; kt < 16; ++kt) {
        const int i0 = wk * 512 + kt * 32;
        const int ibi = i0 + kg * 8;
        const uint4 bq0 = *(const uint4*)(bp + ibi);
        const uint4 bq1 = *(const uint4*)(bp + ibi + 4);
        const uint4 pq0 = *(const uint4*)(PPb + ibi);
        const uint4 pq1 = *(const uint4*)(PPb + ibi + 4);
        const float4 eta = *(const float4*)(ETb + ibi);
        const float4 etc_ = *(const float4*)(ETb + ibi + 4);

        auto pv = [&](uint32 dw, uint32 pp, float etv) -> uint32 {
          const float p1f = __builtin_bit_cast(float, pp << 16);
          const float p2f = __builtin_bit_cast(float, pp & 0xFFFF0000u);
          const float v = (rE1 > etv) ? p1f * rE1 : p2f * rE2;
          return (dw & maskbit) ? __builtin_bit_cast(uint32, v) : 0u;
        };
        uint32 pe[8];
        pe[0] = pv(bq0.x, pq0.x, eta.x);
        pe[1] = pv(bq0.y, pq0.y, eta.y);
        pe[2] = pv(bq0.z, pq0.z, eta.z);
        pe[3] = pv(bq0.w, pq0.w, eta.w);
        pe[4] = pv(bq1.x, pq1.x, etc_.x);
        pe[5] = pv(bq1.y, pq1.y, etc_.y);
        pe[6] = pv(bq1.z, pq1.z, etc_.z);
        pe[7] = pv(bq1.w, pq1.w, etc_.w);

        union { uint32 u4[4]; bf16x8 v; } af;
#pragma unroll
        for (int e = 0; e < 4; ++e)  // truncating bf16 pair-pack (3 ops)
          af.u4[e] = (pe[2 * e + 1] & 0xFFFF0000u) | (pe[2 * e] >> 16);

        const size_t bbase = ((size_t)((i0 >> 3) + kg)) << 9;
#pragma unroll
        for (int dt = 0; dt < 4; ++dt) {
          const bf16x8 bv = *(const bf16x8*)(hTtb + bbase + ((dt * 16 + (l & 15)) << 3));
          acc[dt] = __builtin_amdgcn_mfma_f32_16x16x32_bf16(af.v, bv, acc[dt], 0, 0, 0);
        }
      }

      __syncthreads();  // protect previous iteration's sAcc reads
      if (wk > 0) {
#pragma unroll
        for (int dt = 0; dt < 4; ++dt)
#pragma unroll
          for (int r = 0; r < 4; ++r)
            sAcc[wk - 1][wj * 16 + (l >> 4) * 4 + r][dt * 16 + (l & 15)] = acc[dt][r];
      }
      __syncthreads();
      if (wk == 0) {
#pragma unroll
        for (int dt = 0; dt < 4; ++dt) {
#pragma unroll
          for (int r = 0; r < 4; ++r) {
            const int jrow = wj * 16 + (l >> 4) * 4 + r;
            const int d = dt * 16 + (l & 15);
            float s = acc[dt][r] + sAcc[0][jrow][d] + sAcc[1][jrow][d] + sAcc[2][jrow][d];
            s = s > 0.f ? s : expm1f(s);
            outb[(size_t)(jt * 32 + jrow) * 64 + d] = s;
          }
        }
      }
    }
  }
}

extern "C" void kernel_launch(void* const* d_in, const int* in_sizes, int n_in,
                              void* d_out, int out_size, void* d_ws, size_t ws_size,
                              hipStream_t stream) {
  const float* X = (const float*)d_in[0];     // [8,2048,128] f32
  const int* adj = (const int*)d_in[1];       // [8,2048,2048] i32
  const float* mask = (const float*)d_in[2];  // [8,2048] f32
  const float* W = (const float*)d_in[3];     // [128,64] f32
  const float* A = (const float*)d_in[4];     // [128,1] f32
  float* out = (float*)d_out;                 // [8,2048,64] f32
  char* ws = (char*)d_ws;

  unsigned short* hTt = (unsigned short*)(ws);  // 2 MB (k-blocked)
  float* E1 = (float*)(ws + 2097152);           // 64 KB each
  float* E2 = (float*)(ws + 2162688);
  float* ET = (float*)(ws + 2228224);
  float* G  = (float*)(ws + 2293760);
  uint32* PP = (uint32*)(ws + 2359296);         // 64 KB
  uint32* bitA = (uint32*)(ws + 2424832);       // 2 MB
  uint32* bitB = (uint32*)(ws + 4521984);       // 2 MB (ends 6619136)

  hipLaunchKernelGGL(k1_h_e, dim3(512), dim3(256), 0, stream, X, W, A, mask, hTt, E1, E2, ET, G);

  // Cooperative grid sizing: resident capacity via occupancy query (host-side,
  // capture-safe), multiple of 8 for batch/XCD affinity, capped at work size.
  int nb = 0;
  (void)hipOccupancyMaxActiveBlocksPerMultiprocessor(&nb, kf_fused, 512, 0);
  if (nb < 1) nb = 1;
  int ncu = 256;
  {
    hipDeviceProp_t props;
    int dev = 0;
    if (hipGetDevice(&dev) == hipSuccess &&
        hipGetDeviceProperties(&props, dev) == hipSuccess)
      ncu = props.multiProcessorCount;
  }
  long long grid_ll = (long long)nb * ncu;
  if (grid_ll > 2048) grid_ll = 2048;
  int grid = (int)(grid_ll & ~7LL);
  if (grid < 8) grid = 8;

  void* args[] = {(void*)&adj, (void*)&hTt, (void*)&E1, (void*)&E2, (void*)&ET,
                  (void*)&G, (void*)&bitA, (void*)&bitB, (void*)&PP, (void*)&out};
  (void)hipLaunchCooperativeKernel((const void*)kf_fused, dim3(grid), dim3(512),
                                   args, 0, stream);
}

// Round 6
// 135.776 us; speedup vs baseline: 1.2997x; 1.2997x over previous
//
#include <hip/hip_runtime.h>
#include <stdint.h>

typedef unsigned int uint32;
typedef unsigned long long u64;
typedef short bf16x8 __attribute__((ext_vector_type(8)));
typedef float f32x4 __attribute__((ext_vector_type(4)));

// fp32 -> bf16 bits, round-to-nearest-even
__device__ __forceinline__ unsigned short f2bf(float f) {
  uint32 u = __builtin_bit_cast(uint32, f);
  u += 0x7FFFu + ((u >> 16) & 1u);
  return (unsigned short)(u >> 16);
}

// ---------------------------------------------------------------------------
// K1: h = X*W (16384x128 @ 128x64), e_src/e_dst = h.a, store
//   hTt : bf16, k-blocked layout [B][i>>3][d][i&7]  (256KB/batch)
//   E1 = exp(e_dst), E2 = exp(0.2 e_dst)   (per j)
//   ET = exp(-e_src), G = exp(0.8 e_src)   (per i)
// ---------------------------------------------------------------------------
__global__ __launch_bounds__(256) void k1_h_e(
    const float* __restrict__ X, const float* __restrict__ W,
    const float* __restrict__ A, const float* __restrict__ mask,
    unsigned short* __restrict__ hTt,
    float* __restrict__ E1, float* __restrict__ E2,
    float* __restrict__ ET, float* __restrict__ G) {
  __shared__ float WT[64][132];
  const int t = threadIdx.x;
  for (int idx = t; idx < 128 * 64; idx += 256) {
    int k = idx >> 6, d = idx & 63;
    WT[d][k] = W[idx];
  }
  __syncthreads();

  const int dg = t & 15;
  const int rp = t >> 4;
  const int gi0 = blockIdx.x * 32 + rp * 2;

  float a1[4], a2[4];
#pragma unroll
  for (int dd = 0; dd < 4; ++dd) {
    a1[dd] = A[dg + 16 * dd];
    a2[dd] = A[64 + dg + 16 * dd];
  }

  const float4* x0 = (const float4*)(X + (size_t)gi0 * 128);
  const float4* x1 = (const float4*)(X + (size_t)(gi0 + 1) * 128);
  float h0[4] = {0.f, 0.f, 0.f, 0.f}, h1[4] = {0.f, 0.f, 0.f, 0.f};
#pragma unroll 4
  for (int kq = 0; kq < 32; ++kq) {
    const float4 xa = x0[kq], xb = x1[kq];
#pragma unroll
    for (int dd = 0; dd < 4; ++dd) {
      const float4 w4 = *(const float4*)(&WT[dg + 16 * dd][kq * 4]);
      h0[dd] += xa.x * w4.x + xa.y * w4.y + xa.z * w4.z + xa.w * w4.w;
      h1[dd] += xb.x * w4.x + xb.y * w4.y + xb.z * w4.z + xb.w * w4.w;
    }
  }

  float es0 = 0.f, ed0 = 0.f, es1 = 0.f, ed1 = 0.f;
#pragma unroll
  for (int dd = 0; dd < 4; ++dd) {
    es0 += h0[dd] * a1[dd]; ed0 += h0[dd] * a2[dd];
    es1 += h1[dd] * a1[dd]; ed1 += h1[dd] * a2[dd];
  }
#pragma unroll
  for (int m = 1; m < 16; m <<= 1) {
    es0 += __shfl_xor(es0, m, 64);
    ed0 += __shfl_xor(ed0, m, 64);
    es1 += __shfl_xor(es1, m, 64);
    ed1 += __shfl_xor(ed1, m, 64);
  }
  if (dg == 0) {
    ET[gi0] = expf(-es0);      G[gi0] = expf(0.8f * es0);
    E1[gi0] = expf(ed0);       E2[gi0] = expf(0.2f * ed0);
    ET[gi0 + 1] = expf(-es1);  G[gi0 + 1] = expf(0.8f * es1);
    E1[gi0 + 1] = expf(ed1);   E2[gi0 + 1] = expf(0.2f * ed1);
  }

  const float m0 = mask[gi0], m1 = mask[gi0 + 1];
  const int b = gi0 >> 11, i = gi0 & 2047;
  const int ib = i >> 3, io = i & 7;
#pragma unroll
  for (int dd = 0; dd < 4; ++dd) {
    const int d = dg + 16 * dd;
    const uint32 lo = f2bf(h0[dd] * m0);
    const uint32 hi = f2bf(h1[dd] * m1);
    *(uint32*)(hTt + ((size_t)b << 17) + (ib << 9) + (d << 3) + io) = lo | (hi << 16);
  }
}

// ---------------------------------------------------------------------------
// K3: single streaming read of adj (128MB).
//   per row i: S1 = sum_{edge,pos} E1_j ; S2 = sum_{edge,!pos} E2_j
//   PP[i] = packed bf16 (P1 = 1/(S1+S2/G), P2 = 1/(S1*G+S2))
//   bit planes: bitA/bitB u32 [b][widx][i] = lo/hi dword of the j-ballot
//   (word widx = (j>>8)*4 + (j&3), bit (j>>2)&63)
//   NOTE (round 6): launched 3x for ablation-by-duplication; idempotent.
// ---------------------------------------------------------------------------
__global__ __launch_bounds__(256) void k3_stats(
    const int* __restrict__ adj,
    const float* __restrict__ E1, const float* __restrict__ E2,
    const float* __restrict__ ET, const float* __restrict__ G,
    uint32* __restrict__ bitA, uint32* __restrict__ bitB,
    uint32* __restrict__ PP) {
  const int w = threadIdx.x >> 6, lane = threadIdx.x & 63;
  const int gi = blockIdx.x * 4 + w;
  const int b = gi >> 11, i = gi & 2047;
  const float eti = ET[gi];
  const int4* arow = (const int4*)(adj + (size_t)gi * 2048);
  const float4* e1p = (const float4*)(E1 + b * 2048);
  const float4* e2p = (const float4*)(E2 + b * 2048);
  float s1 = 0.f, s2 = 0.f;
#pragma unroll
  for (int jc = 0; jc < 8; ++jc) {
    const int idx = jc * 64 + lane;
    const int4 av = arow[idx];
    const float4 e1 = e1p[idx];
    const float4 e2 = e2p[idx];
    const bool m0 = (av.x == 1), m1b = (av.y == 1), m2 = (av.z == 1), m3 = (av.w == 1);
    const bool q0 = (e1.x > eti), q1 = (e1.y > eti), q2 = (e1.z > eti), q3 = (e1.w > eti);
    s1 += (m0 && q0) ? e1.x : 0.f;   s2 += (m0 && !q0) ? e2.x : 0.f;
    s1 += (m1b && q1) ? e1.y : 0.f;  s2 += (m1b && !q1) ? e2.y : 0.f;
    s1 += (m2 && q2) ? e1.z : 0.f;   s2 += (m2 && !q2) ? e2.z : 0.f;
    s1 += (m3 && q3) ? e1.w : 0.f;   s2 += (m3 && !q3) ? e2.w : 0.f;
    const u64 b0 = __ballot(m0), b1 = __ballot(m1b), b2 = __ballot(m2), b3 = __ballot(m3);
    if (lane < 4) {
      const u64 v = (lane == 0) ? b0 : (lane == 1) ? b1 : (lane == 2) ? b2 : b3;
      const size_t off = (size_t)(b * 32 + jc * 4 + lane) * 2048 + i;
      bitA[off] = (uint32)v;
      bitB[off] = (uint32)(v >> 32);
    }
  }
#pragma unroll
  for (int m = 1; m < 64; m <<= 1) {
    s1 += __shfl_xor(s1, m, 64);
    s2 += __shfl_xor(s2, m, 64);
  }
  if (lane == 0) {
    const float g = G[gi];
    const bool ok = (s1 + s2) > 0.f;
    const float p1 = ok ? 1.f / (s1 + s2 / g) : 0.f;
    const float p2 = ok ? 1.f / (s1 * g + s2) : 0.f;
    PP[gi] = (uint32)f2bf(p1) | ((uint32)f2bf(p2) << 16);
  }
}

// ---------------------------------------------------------------------------
// K4 (fused agg + reduce + ELU): h'[j,d] = sum_i p[i,j]*h[i,d] via MFMA.
//   block: 512 thr = 8 waves = (wj 0..1 j-subtiles of 16) x (wk 0..3 K-quarters)
//   grid: b = bid&7 (XCD-affine), jt = bid>>3.
//   B-fragments: direct global loads from k-blocked hTt.
// ---------------------------------------------------------------------------
__global__ __launch_bounds__(512) void k4_fused(
    const unsigned short* __restrict__ hTt,
    const uint32* __restrict__ bitA, const uint32* __restrict__ bitB,
    const float* __restrict__ E1, const float* __restrict__ E2,
    const float* __restrict__ ET, const uint32* __restrict__ PP,
    float* __restrict__ out) {
  __shared__ float sAcc[3][32][68];
  const int t = threadIdx.x;
  const int w = t >> 6, l = t & 63;
  const int wj = w & 1, wk = w >> 1;
  const int bid = blockIdx.x;
  const int b = bid & 7;
  const int jt = bid >> 3;
  const int J0 = jt * 32 + wj * 16;
  const int jj = J0 + (l & 15);
  const int kg = l >> 4;

  const float rE1 = E1[b * 2048 + jj];
  const float rE2 = E2[b * 2048 + jj];
  const int widx = ((jj >> 8) << 2) + (jj & 3);
  const size_t rowoff = (size_t)(b * 32 + widx) * 2048;
  const int sh = (jj >> 2) & 63;          // hi/lo wave-uniform (J0 % 16 == 0)
  const uint32 maskbit = 1u << (sh & 31);
  const uint32* bp = ((sh >= 32) ? bitB : bitA) + rowoff;
  const float* ETb = ET + b * 2048;
  const uint32* PPb = PP + b * 2048;
  const unsigned short* hTtb = hTt + ((size_t)b << 17);

  f32x4 acc[4] = {};

  for (int kt = 0; kt < 16; ++kt) {
    const int i0 = wk * 512 + kt * 32;
    const int ibi = i0 + kg * 8;
    const uint4 bq0 = *(const uint4*)(bp + ibi);
    const uint4 bq1 = *(const uint4*)(bp + ibi + 4);
    const uint4 pq0 = *(const uint4*)(PPb + ibi);
    const uint4 pq1 = *(const uint4*)(PPb + ibi + 4);
    const float4 eta = *(const float4*)(ETb + ibi);
    const float4 etc_ = *(const float4*)(ETb + ibi + 4);

    auto pv = [&](uint32 dw, uint32 pp, float etv) -> float {
      const float p1f = __builtin_bit_cast(float, pp << 16);
      const float p2f = __builtin_bit_cast(float, pp & 0xFFFF0000u);
      const float v = (rE1 > etv) ? p1f * rE1 : p2f * rE2;
      return (dw & maskbit) ? v : 0.f;
    };
    float pe[8];
    pe[0] = pv(bq0.x, pq0.x, eta.x);
    pe[1] = pv(bq0.y, pq0.y, eta.y);
    pe[2] = pv(bq0.z, pq0.z, eta.z);
    pe[3] = pv(bq0.w, pq0.w, eta.w);
    pe[4] = pv(bq1.x, pq1.x, etc_.x);
    pe[5] = pv(bq1.y, pq1.y, etc_.y);
    pe[6] = pv(bq1.z, pq1.z, etc_.z);
    pe[7] = pv(bq1.w, pq1.w, etc_.w);

    union { uint32 u[4]; bf16x8 v; } af;
#pragma unroll
    for (int e = 0; e < 4; ++e)
      af.u[e] = (uint32)f2bf(pe[2 * e]) | ((uint32)f2bf(pe[2 * e + 1]) << 16);

    // B-fragment: k-block (i0>>3)+kg, 16 lanes read 16 consecutive d-chunks
    const size_t bbase = ((size_t)((i0 >> 3) + kg)) << 9;
#pragma unroll
    for (int dt = 0; dt < 4; ++dt) {
      const bf16x8 bv = *(const bf16x8*)(hTtb + bbase + ((dt * 16 + (l & 15)) << 3));
      acc[dt] = __builtin_amdgcn_mfma_f32_16x16x32_bf16(af.v, bv, acc[dt], 0, 0, 0);
    }
  }

  // reduce across wk + ELU + store.  C/D: col = lane&15 (d), row = (l>>4)*4+r (j)
  if (wk > 0) {
#pragma unroll
    for (int dt = 0; dt < 4; ++dt)
#pragma unroll
      for (int r = 0; r < 4; ++r)
        sAcc[wk - 1][wj * 16 + (l >> 4) * 4 + r][dt * 16 + (l & 15)] = acc[dt][r];
  }
  __syncthreads();
  if (wk == 0) {
    float* outb = out + ((size_t)b << 17);
#pragma unroll
    for (int dt = 0; dt < 4; ++dt) {
#pragma unroll
      for (int r = 0; r < 4; ++r) {
        const int jrow = wj * 16 + (l >> 4) * 4 + r;
        const int d = dt * 16 + (l & 15);
        float s = acc[dt][r] + sAcc[0][jrow][d] + sAcc[1][jrow][d] + sAcc[2][jrow][d];
        s = s > 0.f ? s : expm1f(s);
        outb[(size_t)(jt * 32 + jrow) * 64 + d] = s;
      }
    }
  }
}

extern "C" void kernel_launch(void* const* d_in, const int* in_sizes, int n_in,
                              void* d_out, int out_size, void* d_ws, size_t ws_size,
                              hipStream_t stream) {
  const float* X = (const float*)d_in[0];     // [8,2048,128] f32
  const int* adj = (const int*)d_in[1];       // [8,2048,2048] i32
  const float* mask = (const float*)d_in[2];  // [8,2048] f32
  const float* W = (const float*)d_in[3];     // [128,64] f32
  const float* A = (const float*)d_in[4];     // [128,1] f32
  float* out = (float*)d_out;                 // [8,2048,64] f32
  char* ws = (char*)d_ws;

  unsigned short* hTt = (unsigned short*)(ws);  // 2 MB (k-blocked)
  float* E1 = (float*)(ws + 2097152);           // 64 KB each
  float* E2 = (float*)(ws + 2162688);
  float* ET = (float*)(ws + 2228224);
  float* G  = (float*)(ws + 2293760);
  uint32* PP = (uint32*)(ws + 2359296);         // 64 KB
  uint32* bitA = (uint32*)(ws + 2424832);       // 2 MB
  uint32* bitB = (uint32*)(ws + 4521984);       // 2 MB (ends 6619136)

  hipLaunchKernelGGL(k1_h_e, dim3(512), dim3(256), 0, stream, X, W, A, mask, hTt, E1, E2, ET, G);
  // MEASUREMENT (round 6): k3 launched 3x (idempotent). k3 = (dur - 83.3)/2.
  hipLaunchKernelGGL(k3_stats, dim3(4096), dim3(256), 0, stream, adj, E1, E2, ET, G, bitA, bitB, PP);
  hipLaunchKernelGGL(k3_stats, dim3(4096), dim3(256), 0, stream, adj, E1, E2, ET, G, bitA, bitB, PP);
  hipLaunchKernelGGL(k3_stats, dim3(4096), dim3(256), 0, stream, adj, E1, E2, ET, G, bitA, bitB, PP);
  hipLaunchKernelGGL(k4_fused, dim3(512), dim3(512), 0, stream, hTt, bitA, bitB, E1, E2, ET, PP, out);
}

// Round 7
// 74.484 us; speedup vs baseline: 2.3693x; 1.8229x over previous
//
#include <hip/hip_runtime.h>
#include <stdint.h>

typedef unsigned int uint32;
typedef unsigned long long u64;
typedef short bf16x8 __attribute__((ext_vector_type(8)));
typedef float f32x4 __attribute__((ext_vector_type(4)));

// fp32 -> bf16 bits, round-to-nearest-even
__device__ __forceinline__ unsigned short f2bf(float f) {
  uint32 u = __builtin_bit_cast(uint32, f);
  u += 0x7FFFu + ((u >> 16) & 1u);
  return (unsigned short)(u >> 16);
}

// ---------------------------------------------------------------------------
// K1: h = X*W (16384x128 @ 128x64), e_src/e_dst = h.a, store
//   hTt : bf16, k-blocked layout [B][i>>3][d][i&7]  (256KB/batch)
//   E1 = exp(e_dst), E2 = exp(0.2 e_dst)   (per j)
//   ET = exp(-e_src), G = exp(0.8 e_src)   (per i)
// ---------------------------------------------------------------------------
__global__ __launch_bounds__(256) void k1_h_e(
    const float* __restrict__ X, const float* __restrict__ W,
    const float* __restrict__ A, const float* __restrict__ mask,
    unsigned short* __restrict__ hTt,
    float* __restrict__ E1, float* __restrict__ E2,
    float* __restrict__ ET, float* __restrict__ G) {
  __shared__ float WT[64][132];
  const int t = threadIdx.x;
  for (int idx = t; idx < 128 * 64; idx += 256) {
    int k = idx >> 6, d = idx & 63;
    WT[d][k] = W[idx];
  }
  __syncthreads();

  const int dg = t & 15;
  const int rp = t >> 4;
  const int gi0 = blockIdx.x * 32 + rp * 2;

  float a1[4], a2[4];
#pragma unroll
  for (int dd = 0; dd < 4; ++dd) {
    a1[dd] = A[dg + 16 * dd];
    a2[dd] = A[64 + dg + 16 * dd];
  }

  const float4* x0 = (const float4*)(X + (size_t)gi0 * 128);
  const float4* x1 = (const float4*)(X + (size_t)(gi0 + 1) * 128);
  float h0[4] = {0.f, 0.f, 0.f, 0.f}, h1[4] = {0.f, 0.f, 0.f, 0.f};
#pragma unroll 4
  for (int kq = 0; kq < 32; ++kq) {
    const float4 xa = x0[kq], xb = x1[kq];
#pragma unroll
    for (int dd = 0; dd < 4; ++dd) {
      const float4 w4 = *(const float4*)(&WT[dg + 16 * dd][kq * 4]);
      h0[dd] += xa.x * w4.x + xa.y * w4.y + xa.z * w4.z + xa.w * w4.w;
      h1[dd] += xb.x * w4.x + xb.y * w4.y + xb.z * w4.z + xb.w * w4.w;
    }
  }

  float es0 = 0.f, ed0 = 0.f, es1 = 0.f, ed1 = 0.f;
#pragma unroll
  for (int dd = 0; dd < 4; ++dd) {
    es0 += h0[dd] * a1[dd]; ed0 += h0[dd] * a2[dd];
    es1 += h1[dd] * a1[dd]; ed1 += h1[dd] * a2[dd];
  }
#pragma unroll
  for (int m = 1; m < 16; m <<= 1) {
    es0 += __shfl_xor(es0, m, 64);
    ed0 += __shfl_xor(ed0, m, 64);
    es1 += __shfl_xor(es1, m, 64);
    ed1 += __shfl_xor(ed1, m, 64);
  }
  if (dg == 0) {
    ET[gi0] = expf(-es0);      G[gi0] = expf(0.8f * es0);
    E1[gi0] = expf(ed0);       E2[gi0] = expf(0.2f * ed0);
    ET[gi0 + 1] = expf(-es1);  G[gi0 + 1] = expf(0.8f * es1);
    E1[gi0 + 1] = expf(ed1);   E2[gi0 + 1] = expf(0.2f * ed1);
  }

  const float m0 = mask[gi0], m1 = mask[gi0 + 1];
  const int b = gi0 >> 11, i = gi0 & 2047;
  const int ib = i >> 3, io = i & 7;
#pragma unroll
  for (int dd = 0; dd < 4; ++dd) {
    const int d = dg + 16 * dd;
    const uint32 lo = f2bf(h0[dd] * m0);
    const uint32 hi = f2bf(h1[dd] * m1);
    *(uint32*)(hTt + ((size_t)b << 17) + (ib << 9) + (d << 3) + io) = lo | (hi << 16);
  }
}

// ---------------------------------------------------------------------------
// K3: single streaming read of adj (128MB). (unchanged, known-good, ~26us)
//   per row i: S1 = sum_{edge,pos} E1_j ; S2 = sum_{edge,!pos} E2_j
//   PP[i] = packed bf16 (P1 = 1/(S1+S2/G), P2 = 1/(S1*G+S2))
//   bit planes: bitA/bitB u32 [b][widx][i] = lo/hi dword of the j-ballot
// ---------------------------------------------------------------------------
__global__ __launch_bounds__(256) void k3_stats(
    const int* __restrict__ adj,
    const float* __restrict__ E1, const float* __restrict__ E2,
    const float* __restrict__ ET, const float* __restrict__ G,
    uint32* __restrict__ bitA, uint32* __restrict__ bitB,
    uint32* __restrict__ PP) {
  const int w = threadIdx.x >> 6, lane = threadIdx.x & 63;
  const int gi = blockIdx.x * 4 + w;
  const int b = gi >> 11, i = gi & 2047;
  const float eti = ET[gi];
  const int4* arow = (const int4*)(adj + (size_t)gi * 2048);
  const float4* e1p = (const float4*)(E1 + b * 2048);
  const float4* e2p = (const float4*)(E2 + b * 2048);
  float s1 = 0.f, s2 = 0.f;
#pragma unroll
  for (int jc = 0; jc < 8; ++jc) {
    const int idx = jc * 64 + lane;
    const int4 av = arow[idx];
    const float4 e1 = e1p[idx];
    const float4 e2 = e2p[idx];
    const bool m0 = (av.x == 1), m1b = (av.y == 1), m2 = (av.z == 1), m3 = (av.w == 1);
    const bool q0 = (e1.x > eti), q1 = (e1.y > eti), q2 = (e1.z > eti), q3 = (e1.w > eti);
    s1 += (m0 && q0) ? e1.x : 0.f;   s2 += (m0 && !q0) ? e2.x : 0.f;
    s1 += (m1b && q1) ? e1.y : 0.f;  s2 += (m1b && !q1) ? e2.y : 0.f;
    s1 += (m2 && q2) ? e1.z : 0.f;   s2 += (m2 && !q2) ? e2.z : 0.f;
    s1 += (m3 && q3) ? e1.w : 0.f;   s2 += (m3 && !q3) ? e2.w : 0.f;
    const u64 b0 = __ballot(m0), b1 = __ballot(m1b), b2 = __ballot(m2), b3 = __ballot(m3);
    if (lane < 4) {
      const u64 v = (lane == 0) ? b0 : (lane == 1) ? b1 : (lane == 2) ? b2 : b3;
      const size_t off = (size_t)(b * 32 + jc * 4 + lane) * 2048 + i;
      bitA[off] = (uint32)v;
      bitB[off] = (uint32)(v >> 32);
    }
  }
#pragma unroll
  for (int m = 1; m < 64; m <<= 1) {
    s1 += __shfl_xor(s1, m, 64);
    s2 += __shfl_xor(s2, m, 64);
  }
  if (lane == 0) {
    const float g = G[gi];
    const bool ok = (s1 + s2) > 0.f;
    const float p1 = ok ? 1.f / (s1 + s2 / g) : 0.f;
    const float p2 = ok ? 1.f / (s1 * g + s2) : 0.f;
    PP[gi] = (uint32)f2bf(p1) | ((uint32)f2bf(p2) << 16);
  }
}

// ---------------------------------------------------------------------------
// K4 v2 (agg + reduce + ELU): h'[j,d] = sum_i p[i,j]*h[i,d] via MFMA.
//   pe = bit ? max(P1_i*E1_j, P2_i*E2_j) : 0   -- max() replaces the leaky
//   branch compare (ratio of branches is e^{0.8 s}); ET eliminated from loop.
//   block: 256 thr = 4 waves = 4 K-quarters of one 16-j tile; grid 1024
//   (b = bid&7 XCD-affine). Explicit next-kt register prefetch of the A-side
//   (bits+PP) so each global load has a full iteration of compute to hide
//   under (the round-4 version was exposed-latency-bound, ~50us).
// ---------------------------------------------------------------------------
__global__ __launch_bounds__(256) void k4_fused(
    const unsigned short* __restrict__ hTt,
    const uint32* __restrict__ bitA, const uint32* __restrict__ bitB,
    const float* __restrict__ E1, const float* __restrict__ E2,
    const uint32* __restrict__ PP, float* __restrict__ out) {
  __shared__ float sAcc[3][16][68];
  const int t = threadIdx.x;
  const int w = t >> 6, l = t & 63;   // w = K-quarter
  const int bid = blockIdx.x;
  const int b = bid & 7;
  const int jt = bid >> 3;            // 0..127
  const int J0 = jt * 16;
  const int jj = J0 + (l & 15);
  const int kg = l >> 4;

  const float rE1 = E1[b * 2048 + jj];
  const float rE2 = E2[b * 2048 + jj];
  const int widx = ((jj >> 8) << 2) + (jj & 3);
  const size_t rowoff = (size_t)(b * 32 + widx) * 2048;
  const int sh = (jj >> 2) & 63;       // plane select uniform per 16-j tile
  const uint32 maskbit = 1u << (sh & 31);
  const uint32* bp = ((sh >= 32) ? bitB : bitA) + rowoff;
  const uint32* PPb = PP + b * 2048;
  const unsigned short* hTtb = hTt + ((size_t)b << 17);

  f32x4 acc[4] = {};

  // prologue: A-side loads for kt = 0
  const int ib0 = w * 512 + kg * 8;
  uint4 bq0 = *(const uint4*)(bp + ib0);
  uint4 bq1 = *(const uint4*)(bp + ib0 + 4);
  uint4 pq0 = *(const uint4*)(PPb + ib0);
  uint4 pq1 = *(const uint4*)(PPb + ib0 + 4);

#pragma unroll
  for (int kt = 0; kt < 16; ++kt) {
    const int i0 = w * 512 + kt * 32;

    // B-fragment loads for current kt (k-blocked hTt: 256B-contig / 16 lanes)
    const size_t bbase = ((size_t)((i0 >> 3) + kg)) << 9;
    const bf16x8 bv0 = *(const bf16x8*)(hTtb + bbase + (((l & 15) + 0) << 3));
    const bf16x8 bv1 = *(const bf16x8*)(hTtb + bbase + (((l & 15) + 16) << 3));
    const bf16x8 bv2 = *(const bf16x8*)(hTtb + bbase + (((l & 15) + 32) << 3));
    const bf16x8 bv3 = *(const bf16x8*)(hTtb + bbase + (((l & 15) + 48) << 3));

    // prefetch A-side for kt+1
    uint4 nbq0 = bq0, nbq1 = bq1, npq0 = pq0, npq1 = pq1;
    if (kt < 15) {
      const int ni = i0 + 32 + kg * 8;
      nbq0 = *(const uint4*)(bp + ni);
      nbq1 = *(const uint4*)(bp + ni + 4);
      npq0 = *(const uint4*)(PPb + ni);
      npq1 = *(const uint4*)(PPb + ni + 4);
    }

    // pe values from current A-side registers
    auto pv = [&](uint32 dw, uint32 pp) -> uint32 {
      const float p1f = __builtin_bit_cast(float, pp << 16);
      const float p2f = __builtin_bit_cast(float, pp & 0xFFFF0000u);
      const float v = fmaxf(p1f * rE1, p2f * rE2);
      return (dw & maskbit) ? __builtin_bit_cast(uint32, v) : 0u;
    };
    uint32 pe[8];
    pe[0] = pv(bq0.x, pq0.x);
    pe[1] = pv(bq0.y, pq0.y);
    pe[2] = pv(bq0.z, pq0.z);
    pe[3] = pv(bq0.w, pq0.w);
    pe[4] = pv(bq1.x, pq1.x);
    pe[5] = pv(bq1.y, pq1.y);
    pe[6] = pv(bq1.z, pq1.z);
    pe[7] = pv(bq1.w, pq1.w);

    union { uint32 u4[4]; bf16x8 v; } af;
#pragma unroll
    for (int e = 0; e < 4; ++e)  // truncating bf16 pair-pack
      af.u4[e] = (pe[2 * e + 1] & 0xFFFF0000u) | (pe[2 * e] >> 16);

    acc[0] = __builtin_amdgcn_mfma_f32_16x16x32_bf16(af.v, bv0, acc[0], 0, 0, 0);
    acc[1] = __builtin_amdgcn_mfma_f32_16x16x32_bf16(af.v, bv1, acc[1], 0, 0, 0);
    acc[2] = __builtin_amdgcn_mfma_f32_16x16x32_bf16(af.v, bv2, acc[2], 0, 0, 0);
    acc[3] = __builtin_amdgcn_mfma_f32_16x16x32_bf16(af.v, bv3, acc[3], 0, 0, 0);

    bq0 = nbq0; bq1 = nbq1; pq0 = npq0; pq1 = npq1;
  }

  // reduce across K-quarters + ELU.  C/D: col = l&15 (d), row = (l>>4)*4+r (j)
  if (w > 0) {
#pragma unroll
    for (int dt = 0; dt < 4; ++dt)
#pragma unroll
      for (int r = 0; r < 4; ++r)
        sAcc[w - 1][(l >> 4) * 4 + r][dt * 16 + (l & 15)] = acc[dt][r];
  }
  __syncthreads();
  if (w == 0) {
    float* outb = out + ((size_t)b << 17);
#pragma unroll
    for (int dt = 0; dt < 4; ++dt) {
#pragma unroll
      for (int r = 0; r < 4; ++r) {
        const int jrow = (l >> 4) * 4 + r;
        const int d = dt * 16 + (l & 15);
        float s = acc[dt][r] + sAcc[0][jrow][d] + sAcc[1][jrow][d] + sAcc[2][jrow][d];
        s = s > 0.f ? s : expm1f(s);
        outb[(size_t)(J0 + jrow) * 64 + d] = s;
      }
    }
  }
}

extern "C" void kernel_launch(void* const* d_in, const int* in_sizes, int n_in,
                              void* d_out, int out_size, void* d_ws, size_t ws_size,
                              hipStream_t stream) {
  const float* X = (const float*)d_in[0];     // [8,2048,128] f32
  const int* adj = (const int*)d_in[1];       // [8,2048,2048] i32
  const float* mask = (const float*)d_in[2];  // [8,2048] f32
  const float* W = (const float*)d_in[3];     // [128,64] f32
  const float* A = (const float*)d_in[4];     // [128,1] f32
  float* out = (float*)d_out;                 // [8,2048,64] f32
  char* ws = (char*)d_ws;

  unsigned short* hTt = (unsigned short*)(ws);  // 2 MB (k-blocked)
  float* E1 = (float*)(ws + 2097152);           // 64 KB each
  float* E2 = (float*)(ws + 2162688);
  float* ET = (float*)(ws + 2228224);
  float* G  = (float*)(ws + 2293760);
  uint32* PP = (uint32*)(ws + 2359296);         // 64 KB
  uint32* bitA = (uint32*)(ws + 2424832);       // 2 MB
  uint32* bitB = (uint32*)(ws + 4521984);       // 2 MB (ends 6619136)

  hipLaunchKernelGGL(k1_h_e, dim3(512), dim3(256), 0, stream, X, W, A, mask, hTt, E1, E2, ET, G);
  hipLaunchKernelGGL(k3_stats, dim3(4096), dim3(256), 0, stream, adj, E1, E2, ET, G, bitA, bitB, PP);
  hipLaunchKernelGGL(k4_fused, dim3(1024), dim3(256), 0, stream, hTt, bitA, bitB, E1, E2, PP, out);
}